// Round 3
// baseline (178.849 us; speedup 1.0000x reference)
//
#include <hip/hip_runtime.h>
#include <stdint.h>

#define BROWS 16384
#define CDIM  4096
#define NCLS  64
#define BLKLEN 819u

typedef __attribute__((ext_vector_type(4))) float f32x4;
typedef __attribute__((ext_vector_type(8))) short s16x8;           // 8 bf16 (4 VGPRs) - MFMA A/B frag
typedef __attribute__((ext_vector_type(4))) unsigned short u16x4;

// fp32 -> bf16 bits, round-to-nearest-even
static __device__ __forceinline__ unsigned short f2bf(float f) {
    union { float f; unsigned u; } v; v.f = f;
    unsigned u = v.u;
    u += 0x7FFFu + ((u >> 16) & 1u);
    return (unsigned short)(u >> 16);
}

// Pre-convert W (64 x 4096 fp32) to bf16 bits in workspace. 65536 float4s.
__global__ __launch_bounds__(256) void convert_w_kernel(const float* __restrict__ W,
                                                        unsigned short* __restrict__ Wb) {
    int i = blockIdx.x * 256 + threadIdx.x;   // 0..65535
    f32x4 v = reinterpret_cast<const f32x4*>(W)[i];
    u16x4 o;
    o[0] = f2bf(v[0]); o[1] = f2bf(v[1]); o[2] = f2bf(v[2]); o[3] = f2bf(v[3]);
    reinterpret_cast<u16x4*>(Wb)[i] = o;
}

// Masked skinny GEMM: out[M=16384, N=64] = mask(x) @ W^T + b
// N-split: block = 16 rows; wave wv = those 16 rows x cols [wv*16, wv*16+16).
// Grid = 1024 blocks x 4 waves = 4096 waves = 4 waves/SIMD.
template<bool PRECONV>
__global__ __launch_bounds__(256) void dropblock_gemm_kernel(
    const float* __restrict__ x,
    const float* __restrict__ Wf,            // fp32 W (fallback path)
    const unsigned short* __restrict__ Wb,   // bf16 W (fast path)
    const float* __restrict__ bias,
    const int* __restrict__ starts,
    float* __restrict__ out)
{
    const int lane = threadIdx.x & 63;
    const int wv   = threadIdx.x >> 6;       // wave 0..3 -> N-tile
    const int l16  = lane & 15;
    const int lg   = lane >> 4;              // 0..3
    const int row_base = blockIdx.x * 16;

    // A-fragment row for this lane (layout: row = lane&15, k = (lane>>4)*8 + j)
    const int   s    = starts[row_base + l16];
    const int   koff = lg * 8;
    const float* xrow = x + (size_t)(row_base + l16) * CDIM;
    // B-fragment: W row = wv*16 + (lane&15), same k slice
    const unsigned short* wrow_b = PRECONV ? (Wb + (size_t)(wv * 16 + l16) * CDIM) : nullptr;
    const float*          wrow_f = Wf + (size_t)(wv * 16 + l16) * CDIM;

    f32x4 acc = (f32x4){0.f, 0.f, 0.f, 0.f};

    #pragma unroll 4
    for (int k0 = 0; k0 < CDIM; k0 += 32) {
        const int c0 = k0 + koff;
        f32x4 xa = *reinterpret_cast<const f32x4*>(xrow + c0);
        f32x4 xb = *reinterpret_cast<const f32x4*>(xrow + c0 + 4);

        s16x8 bfrag;
        if (PRECONV) {
            bfrag = *reinterpret_cast<const s16x8*>(wrow_b + c0);
        } else {
            f32x4 wa = *reinterpret_cast<const f32x4*>(wrow_f + c0);
            f32x4 wb = *reinterpret_cast<const f32x4*>(wrow_f + c0 + 4);
            #pragma unroll
            for (int j = 0; j < 4; ++j) {
                bfrag[j]     = (short)f2bf(wa[j]);
                bfrag[j + 4] = (short)f2bf(wb[j]);
            }
        }

        const int d0 = c0 - s;               // keep element iff (unsigned)(c - s) >= 819
        s16x8 afrag;
        #pragma unroll
        for (int j = 0; j < 4; ++j) {
            float va = ((unsigned)(d0 + j)     >= BLKLEN) ? xa[j] : 0.f;
            float vb = ((unsigned)(d0 + 4 + j) >= BLKLEN) ? xb[j] : 0.f;
            afrag[j]     = (short)f2bf(va);
            afrag[j + 4] = (short)f2bf(vb);
        }

        acc = __builtin_amdgcn_mfma_f32_16x16x32_bf16(afrag, bfrag, acc, 0, 0, 0);
    }

    // Epilogue. C/D layout: col = lane&15, row = (lane>>4)*4 + i
    const float bb = bias[wv * 16 + l16];
    #pragma unroll
    for (int i = 0; i < 4; ++i) {
        out[(size_t)(row_base + lg * 4 + i) * NCLS + wv * 16 + l16] = acc[i] + bb;
    }
}

extern "C" void kernel_launch(void* const* d_in, const int* in_sizes, int n_in,
                              void* d_out, int out_size, void* d_ws, size_t ws_size,
                              hipStream_t stream) {
    const float* x      = (const float*)d_in[0];
    const float* W      = (const float*)d_in[1];
    const float* b      = (const float*)d_in[2];
    const int*   starts = (const int*)d_in[3];
    float*       out    = (float*)d_out;

    const size_t wbytes = (size_t)NCLS * CDIM * sizeof(unsigned short);  // 512 KB
    if (ws_size >= wbytes) {
        unsigned short* Wb = (unsigned short*)d_ws;
        convert_w_kernel<<<256, 256, 0, stream>>>(W, Wb);
        dropblock_gemm_kernel<true><<<BROWS / 16, 256, 0, stream>>>(x, W, Wb, b, starts, out);
    } else {
        dropblock_gemm_kernel<false><<<BROWS / 16, 256, 0, stream>>>(x, W, nullptr, b, starts, out);
    }
}

// Round 4
// 102.925 us; speedup vs baseline: 1.7377x; 1.7377x over previous
//
#include <hip/hip_runtime.h>
#include <stdint.h>

#define BROWS 16384
#define CDIM  4096
#define NCLS  64
#define BLKLEN 819u
#define NWAVES 8
#define KCHUNK (CDIM / NWAVES)   // 512 per wave

typedef __attribute__((ext_vector_type(4))) float f32x4;
typedef __attribute__((ext_vector_type(2))) float f32x2;
typedef __attribute__((ext_vector_type(8))) short s16x8;           // 8 bf16 (4 VGPRs) - MFMA A/B frag
typedef __attribute__((ext_vector_type(4))) unsigned short u16x4;

// fp32 -> bf16 bits, round-to-nearest-even
static __device__ __forceinline__ unsigned short f2bf(float f) {
    union { float f; unsigned u; } v; v.f = f;
    unsigned u = v.u;
    u += 0x7FFFu + ((u >> 16) & 1u);
    return (unsigned short)(u >> 16);
}

// Pre-convert W (64 x 4096 fp32) to bf16 bits in workspace. 65536 float4s.
__global__ __launch_bounds__(256) void convert_w_kernel(const float* __restrict__ W,
                                                        unsigned short* __restrict__ Wb) {
    int i = blockIdx.x * 256 + threadIdx.x;   // 0..65535
    f32x4 v = reinterpret_cast<const f32x4*>(W)[i];
    u16x4 o;
    o[0] = f2bf(v[0]); o[1] = f2bf(v[1]); o[2] = f2bf(v[2]); o[3] = f2bf(v[3]);
    reinterpret_cast<u16x4*>(Wb)[i] = o;
}

// Masked skinny GEMM: out[M=16384, N=64] = mask(x) @ W^T + b
// Split-K: block = 16 rows x 8 waves (512 thr); wave wv covers k in
// [wv*512, wv*512+512) for all 64 cols. x read exactly once per block.
// Grid = 1024 blocks -> 8192 waves = 8 waves/SIMD (100% occupancy).
template<bool PRECONV>
__global__ __launch_bounds__(512, 8) void dropblock_gemm_kernel(
    const float* __restrict__ x,
    const float* __restrict__ Wf,            // fp32 W (fallback path)
    const unsigned short* __restrict__ Wb,   // bf16 W (fast path)
    const float* __restrict__ bias,
    const int* __restrict__ starts,
    float* __restrict__ out)
{
    const int lane = threadIdx.x & 63;
    const int wv   = threadIdx.x >> 6;       // wave 0..7 -> K-chunk
    const int l16  = lane & 15;
    const int lg   = lane >> 4;              // 0..3
    const int row_base = blockIdx.x * 16;

    // A-fragment row for this lane (layout: row = lane&15, k = (lane>>4)*8 + j)
    const int   s     = starts[row_base + l16];
    const int   koff  = lg * 8;
    const int   kbase = wv * KCHUNK;
    const float* xrow = x + (size_t)(row_base + l16) * CDIM;

    f32x4 acc[4];
    #pragma unroll
    for (int t = 0; t < 4; ++t) acc[t] = (f32x4){0.f, 0.f, 0.f, 0.f};

    #pragma unroll 4
    for (int k0 = 0; k0 < KCHUNK; k0 += 32) {
        const int c0 = kbase + k0 + koff;
        f32x4 xa = *reinterpret_cast<const f32x4*>(xrow + c0);
        f32x4 xb = *reinterpret_cast<const f32x4*>(xrow + c0 + 4);

        const int d0 = c0 - s;               // keep element iff (unsigned)(c - s) >= 819
        s16x8 afrag;
        #pragma unroll
        for (int j = 0; j < 4; ++j) {
            float va = ((unsigned)(d0 + j)     >= BLKLEN) ? xa[j] : 0.f;
            float vb = ((unsigned)(d0 + 4 + j) >= BLKLEN) ? xb[j] : 0.f;
            afrag[j]     = (short)f2bf(va);
            afrag[j + 4] = (short)f2bf(vb);
        }

        #pragma unroll
        for (int t = 0; t < 4; ++t) {
            s16x8 bfrag;
            if (PRECONV) {
                bfrag = *reinterpret_cast<const s16x8*>(Wb + (size_t)(t * 16 + l16) * CDIM + c0);
            } else {
                const float* wrow = Wf + (size_t)(t * 16 + l16) * CDIM + c0;
                f32x4 wa = *reinterpret_cast<const f32x4*>(wrow);
                f32x4 wb = *reinterpret_cast<const f32x4*>(wrow + 4);
                #pragma unroll
                for (int j = 0; j < 4; ++j) {
                    bfrag[j]     = (short)f2bf(wa[j]);
                    bfrag[j + 4] = (short)f2bf(wb[j]);
                }
            }
            acc[t] = __builtin_amdgcn_mfma_f32_16x16x32_bf16(afrag, bfrag, acc[t], 0, 0, 0);
        }
    }

    // Partials -> LDS. C/D layout: col = lane&15, row = (lane>>4)*4 + i
    __shared__ float plds[NWAVES][16][64];   // 32 KB
    #pragma unroll
    for (int t = 0; t < 4; ++t)
        #pragma unroll
        for (int i = 0; i < 4; ++i)
            plds[wv][lg * 4 + i][t * 16 + l16] = acc[t][i];
    __syncthreads();

    // Reduce 8 partials + bias. 512 threads x 2 floats = 1024 outputs.
    const int tid = threadIdx.x;
    const int row = tid >> 5;                // 0..15
    const int col = (tid & 31) * 2;          // 0,2,..,62
    f32x2 sum = (f32x2){bias[col], bias[col + 1]};
    #pragma unroll
    for (int w = 0; w < NWAVES; ++w) {
        sum[0] += plds[w][row][col];
        sum[1] += plds[w][row][col + 1];
    }
    *reinterpret_cast<f32x2*>(out + (size_t)(row_base + row) * NCLS + col) = sum;
}

extern "C" void kernel_launch(void* const* d_in, const int* in_sizes, int n_in,
                              void* d_out, int out_size, void* d_ws, size_t ws_size,
                              hipStream_t stream) {
    const float* x      = (const float*)d_in[0];
    const float* W      = (const float*)d_in[1];
    const float* b      = (const float*)d_in[2];
    const int*   starts = (const int*)d_in[3];
    float*       out    = (float*)d_out;

    const size_t wbytes = (size_t)NCLS * CDIM * sizeof(unsigned short);  // 512 KB
    if (ws_size >= wbytes) {
        unsigned short* Wb = (unsigned short*)d_ws;
        convert_w_kernel<<<256, 256, 0, stream>>>(W, Wb);
        dropblock_gemm_kernel<true><<<BROWS / 16, 512, 0, stream>>>(x, W, Wb, b, starts, out);
    } else {
        dropblock_gemm_kernel<false><<<BROWS / 16, 512, 0, stream>>>(x, W, nullptr, b, starts, out);
    }
}

// Round 5
// 71.406 us; speedup vs baseline: 2.5047x; 1.4414x over previous
//
#include <hip/hip_runtime.h>
#include <stdint.h>

#define BROWS 16384
#define CDIM  4096
#define NCLS  64
#define BLKLEN 819u
#define NWAVES 8
#define KC 512                    // chunk columns (floats)
#define NCHUNK (CDIM / KC)        // 8

typedef __attribute__((ext_vector_type(4))) float f32x4;
typedef __attribute__((ext_vector_type(2))) float f32x2;
typedef __attribute__((ext_vector_type(8))) short s16x8;   // 8 bf16 - MFMA A/B frag

// fp32 -> bf16 bits, round-to-nearest-even
static __device__ __forceinline__ unsigned short f2bf(float f) {
    union { float f; unsigned u; } v; v.f = f;
    unsigned u = v.u;
    u += 0x7FFFu + ((u >> 16) & 1u);
    return (unsigned short)(u >> 16);
}

static __device__ __forceinline__ void gload_lds16(const void* g, void* l) {
    __builtin_amdgcn_global_load_lds(
        (const __attribute__((address_space(1))) unsigned int*)g,
        (__attribute__((address_space(3))) unsigned int*)l,
        16, 0, 0);
}

// One-time W relayout to FRAGMENT-MAJOR bf16:
// unit u = (kk*4 + t)*64 + lane  (16B each) holds
//   bf16x8 of W[t*16 + (lane&15)][kk*32 + (lane>>4)*8 .. +8)
// so the main loop's bfrag load is a contiguous 1KB wave read.
__global__ __launch_bounds__(256) void convert_w_fragmajor(const float* __restrict__ W,
                                                           unsigned short* __restrict__ Wfm) {
    const int u    = blockIdx.x * 256 + threadIdx.x;   // 0..32767
    const int lane = u & 63;
    const int t    = (u >> 6) & 3;
    const int kk   = u >> 8;
    const int row  = t * 16 + (lane & 15);
    const int col  = kk * 32 + (lane >> 4) * 8;
    const float* p = W + (size_t)row * CDIM + col;
    f32x4 a = *reinterpret_cast<const f32x4*>(p);
    f32x4 b = *reinterpret_cast<const f32x4*>(p + 4);
    s16x8 o;
    #pragma unroll
    for (int j = 0; j < 4; ++j) {
        o[j]     = (short)f2bf(a[j]);
        o[j + 4] = (short)f2bf(b[j]);
    }
    *reinterpret_cast<s16x8*>(Wfm + (size_t)u * 8) = o;
}

// Masked skinny GEMM: out[16384,64] = mask(x) @ W^T + b
// Block = 16 rows x 8 waves (512 thr), split-K per wave. x staged to LDS in
// 16x512 chunks (double-buffered) via global_load_lds with pre-swizzled source;
// ds_read uses XOR swizzle ((row&7)<<4) -> conflict-free. W loads frag-major.
template<bool PRECONV>
__global__ __launch_bounds__(512, 4) void dropblock_gemm_kernel(
    const float* __restrict__ x,
    const float* __restrict__ Wf,            // fp32 W (fallback)
    const unsigned short* __restrict__ Wfm,  // frag-major bf16 W
    const float* __restrict__ bias,
    const int* __restrict__ starts,
    float* __restrict__ out)
{
    __shared__ float lds[2][16][KC];         // 64 KB
    const int tid  = threadIdx.x;
    const int lane = tid & 63;
    const int wv   = tid >> 6;               // wave 0..7 -> K-slice
    const int l16  = lane & 15;
    const int lg   = lane >> 4;              // 0..3
    const int row_base = blockIdx.x * 16;

    const int s = starts[row_base + l16];
    const unsigned swzA = (unsigned)((l16 & 7) << 4);   // read-side XOR for this lane's row

    f32x4 acc[4];
    #pragma unroll
    for (int t = 0; t < 4; ++t) acc[t] = (f32x4){0.f, 0.f, 0.f, 0.f};

    // ---- stage chunk ch into buffer b (all 512 threads; 4 x 16B each) ----
    // linear LDS unit u = i*512 + wv*64 + lane ; row r = u>>7 (wave-uniform);
    // source byte within row = ((u&127)*16) ^ ((r&7)<<4)  -> contiguous 1KB per
    // wave instruction, lane-permuted to pre-apply the read swizzle.
    auto stage = [&](int ch, int b) {
        char* lbase = (char*)lds + b * (16 * KC * 4);
        #pragma unroll
        for (int i = 0; i < 4; ++i) {
            const int r  = i * 4 + (wv >> 1);                 // wave-uniform row
            const unsigned wb = (unsigned)(((wv & 1) * 64 + lane) * 16) ^ (unsigned)((r & 7) << 4);
            const char* g = (const char*)x
                + ((size_t)(row_base + r) * CDIM + (size_t)ch * KC) * 4 + wb;
            gload_lds16(g, lbase + i * 8192 + wv * 1024);
        }
    };

    stage(0, 0);
    __syncthreads();

    for (int ch = 0; ch < NCHUNK; ++ch) {
        const int b = ch & 1;
        if (ch + 1 < NCHUNK) stage(ch + 1, b ^ 1);

        const char* lbase = (const char*)lds + b * (16 * KC * 4);
        #pragma unroll
        for (int c = 0; c < 2; ++c) {
            const int kl = wv * 64 + c * 32;                  // col in chunk
            const int a0 = l16 * 2048 + (kl + lg * 8) * 4;    // linear byte addr
            f32x4 xa = *reinterpret_cast<const f32x4*>(lbase + ((unsigned)a0 ^ swzA));
            f32x4 xb = *reinterpret_cast<const f32x4*>(lbase + ((unsigned)(a0 + 16) ^ swzA));

            const int d0 = ch * KC + kl + lg * 8 - s;         // keep iff (unsigned)(c-s) >= 819
            s16x8 afrag;
            #pragma unroll
            for (int j = 0; j < 4; ++j) {
                float va = ((unsigned)(d0 + j)     >= BLKLEN) ? xa[j] : 0.f;
                float vb = ((unsigned)(d0 + 4 + j) >= BLKLEN) ? xb[j] : 0.f;
                afrag[j]     = (short)f2bf(va);
                afrag[j + 4] = (short)f2bf(vb);
            }

            const int kk = ch * 16 + wv * 2 + c;              // global k0/32 index
            #pragma unroll
            for (int t = 0; t < 4; ++t) {
                s16x8 bfrag;
                if (PRECONV) {
                    bfrag = *reinterpret_cast<const s16x8*>(
                        Wfm + ((size_t)((kk * 4 + t) * 64 + lane)) * 8);
                } else {
                    const float* wrow = Wf + (size_t)(t * 16 + l16) * CDIM + kk * 32 + lg * 8;
                    f32x4 wa = *reinterpret_cast<const f32x4*>(wrow);
                    f32x4 wb = *reinterpret_cast<const f32x4*>(wrow + 4);
                    #pragma unroll
                    for (int j = 0; j < 4; ++j) {
                        bfrag[j]     = (short)f2bf(wa[j]);
                        bfrag[j + 4] = (short)f2bf(wb[j]);
                    }
                }
                acc[t] = __builtin_amdgcn_mfma_f32_16x16x32_bf16(afrag, bfrag, acc[t], 0, 0, 0);
            }
        }
        __syncthreads();
    }

    // Partials -> LDS (reuse buffer 0 region; last chunk read buffer 1).
    float (*plds)[16][64] = reinterpret_cast<float (*)[16][64]>(&lds[0][0][0]);  // 32 KB
    #pragma unroll
    for (int t = 0; t < 4; ++t)
        #pragma unroll
        for (int i = 0; i < 4; ++i)
            plds[wv][lg * 4 + i][t * 16 + l16] = acc[t][i];
    __syncthreads();

    // Reduce 8 partials + bias. 512 threads x 2 floats = 1024 outputs.
    const int row = tid >> 5;                // 0..15
    const int col = (tid & 31) * 2;          // 0,2,..,62
    f32x2 sum = (f32x2){bias[col], bias[col + 1]};
    #pragma unroll
    for (int w = 0; w < NWAVES; ++w) {
        sum[0] += plds[w][row][col];
        sum[1] += plds[w][row][col + 1];
    }
    *reinterpret_cast<f32x2*>(out + (size_t)(row_base + row) * NCLS + col) = sum;
}

extern "C" void kernel_launch(void* const* d_in, const int* in_sizes, int n_in,
                              void* d_out, int out_size, void* d_ws, size_t ws_size,
                              hipStream_t stream) {
    const float* x      = (const float*)d_in[0];
    const float* W      = (const float*)d_in[1];
    const float* b      = (const float*)d_in[2];
    const int*   starts = (const int*)d_in[3];
    float*       out    = (float*)d_out;

    const size_t wbytes = (size_t)NCLS * CDIM * sizeof(unsigned short);  // 512 KB
    if (ws_size >= wbytes) {
        unsigned short* Wfm = (unsigned short*)d_ws;
        convert_w_fragmajor<<<128, 256, 0, stream>>>(W, Wfm);
        dropblock_gemm_kernel<true><<<BROWS / 16, 512, 0, stream>>>(x, W, Wfm, b, starts, out);
    } else {
        dropblock_gemm_kernel<false><<<BROWS / 16, 512, 0, stream>>>(x, W, nullptr, b, starts, out);
    }
}

// Round 6
// 65.351 us; speedup vs baseline: 2.7367x; 1.0926x over previous
//
#include <hip/hip_runtime.h>
#include <stdint.h>

#define BROWS 16384
#define CDIM  4096
#define NCLS  64
#define BLKLEN 819u
#define NWAVES 8
#define CH 512                    // block K-step per chunk (floats)
#define NCHUNK (CDIM / CH)        // 8

typedef __attribute__((ext_vector_type(4))) float f32x4;
typedef __attribute__((ext_vector_type(2))) float f32x2;
typedef __attribute__((ext_vector_type(8))) short s16x8;   // 8 bf16 - MFMA A/B frag

// fp32 -> bf16 bits, round-to-nearest-even
static __device__ __forceinline__ unsigned short f2bf(float f) {
    union { float f; unsigned u; } v; v.f = f;
    unsigned u = v.u;
    u += 0x7FFFu + ((u >> 16) & 1u);
    return (unsigned short)(u >> 16);
}

static __device__ __forceinline__ void gload_lds16(const void* g, void* l) {
    __builtin_amdgcn_global_load_lds(
        (const __attribute__((address_space(1))) unsigned int*)g,
        (__attribute__((address_space(3))) unsigned int*)l,
        16, 0, 0);
}

// One-time W relayout to FRAGMENT-MAJOR bf16:
// unit u = (kk*4 + t)*64 + lane (16B each) holds bf16x8 of
//   W[t*16 + (lane&15)][kk*32 + (lane>>4)*8 .. +8)
__global__ __launch_bounds__(256) void convert_w_fragmajor(const float* __restrict__ W,
                                                           unsigned short* __restrict__ Wfm) {
    const int u    = blockIdx.x * 256 + threadIdx.x;   // 0..32767
    const int lane = u & 63;
    const int t    = (u >> 6) & 3;
    const int kk   = u >> 8;
    const int row  = t * 16 + (lane & 15);
    const int col  = kk * 32 + (lane >> 4) * 8;
    const float* p = W + (size_t)row * CDIM + col;
    f32x4 a = *reinterpret_cast<const f32x4*>(p);
    f32x4 b = *reinterpret_cast<const f32x4*>(p + 4);
    s16x8 o;
    #pragma unroll
    for (int j = 0; j < 4; ++j) {
        o[j]     = (short)f2bf(a[j]);
        o[j + 4] = (short)f2bf(b[j]);
    }
    *reinterpret_cast<s16x8*>(Wfm + (size_t)u * 8) = o;
}

// Masked skinny GEMM: out[16384,64] = mask(x) @ W^T + b
// Block = 16 rows x 8 waves (512 thr), split-K. Wave-PRIVATE double-buffered
// LDS staging (4KB x 2 per wave) via global_load_lds + counted vmcnt —
// NO __syncthreads in the main loop.
template<bool PRECONV>
__global__ __launch_bounds__(512, 4) void dropblock_gemm_kernel(
    const float* __restrict__ x,
    const float* __restrict__ Wf,            // fp32 W (fallback)
    const unsigned short* __restrict__ Wfm,  // frag-major bf16 W
    const float* __restrict__ bias,
    const int* __restrict__ starts,
    float* __restrict__ out)
{
    __shared__ float lds[NWAVES][2][16][64]; // 64 KB; 8 KB private per wave
    const int tid  = threadIdx.x;
    const int lane = tid & 63;
    const int wv   = tid >> 6;               // wave 0..7 -> K-slice
    const int l16  = lane & 15;
    const int lg   = lane >> 4;              // 0..3
    const int row_base = blockIdx.x * 16;

    const int s = starts[row_base + l16];
    const unsigned swzA = (unsigned)((l16 & 7) << 4);
    char* mybuf = (char*)&lds[wv][0][0][0];

    f32x4 acc[4];
    #pragma unroll
    for (int t = 0; t < 4; ++t) acc[t] = (f32x4){0.f, 0.f, 0.f, 0.f};

    // Stage chunk ch (this wave's 16x64 f32 subtile) into private buffer b.
    // LDS linear unit u = i*64+lane -> row r = i*4+(lane>>4), slot (lane&15);
    // source byte pre-swizzled so reads can XOR the same involution.
    auto stage = [&](int ch, int b) {
        const size_t colbase = (size_t)ch * CH + (size_t)wv * 64;
        char* lb = mybuf + b * 4096;
        #pragma unroll
        for (int i = 0; i < 4; ++i) {
            const int r = i * 4 + (lane >> 4);
            const unsigned wb = ((unsigned)((lane & 15) * 16)) ^ ((unsigned)((r & 7) << 4));
            const char* g = (const char*)x + ((size_t)(row_base + r) * CDIM + colbase) * 4 + wb;
            gload_lds16(g, lb + i * 1024);
        }
    };

    stage(0, 0);

    #pragma unroll
    for (int ch = 0; ch < NCHUNK; ++ch) {
        const int b = ch & 1;

        // W fragments for this chunk — issued BEFORE the next stage so the
        // counted vmcnt below covers them exactly (FIFO).
        s16x8 bf[2][4];
        #pragma unroll
        for (int c = 0; c < 2; ++c) {
            const int kk = ch * 16 + wv * 2 + c;
            #pragma unroll
            for (int t = 0; t < 4; ++t) {
                if (PRECONV) {
                    bf[c][t] = *reinterpret_cast<const s16x8*>(
                        Wfm + ((size_t)((kk * 4 + t) * 64 + lane)) * 8);
                } else {
                    const float* wrow = Wf + (size_t)(t * 16 + l16) * CDIM + kk * 32 + lg * 8;
                    f32x4 wa = *reinterpret_cast<const f32x4*>(wrow);
                    f32x4 wb2 = *reinterpret_cast<const f32x4*>(wrow + 4);
                    #pragma unroll
                    for (int j = 0; j < 4; ++j) {
                        bf[c][t][j]     = (short)f2bf(wa[j]);
                        bf[c][t][j + 4] = (short)f2bf(wb2[j]);
                    }
                }
            }
        }

        if (ch + 1 < NCHUNK) stage(ch + 1, b ^ 1);

        __builtin_amdgcn_sched_barrier(0);
        if (ch + 1 < NCHUNK) {
            asm volatile("s_waitcnt vmcnt(4)" ::: "memory");   // chunk ch staged; ch+1 in flight
        } else {
            asm volatile("s_waitcnt vmcnt(0)" ::: "memory");
        }
        __builtin_amdgcn_sched_barrier(0);

        const char* lb = mybuf + b * 4096;
        #pragma unroll
        for (int c = 0; c < 2; ++c) {
            const int a0 = l16 * 256 + c * 128 + lg * 32;
            f32x4 xa = *reinterpret_cast<const f32x4*>(lb + ((unsigned)a0 ^ swzA));
            f32x4 xb = *reinterpret_cast<const f32x4*>(lb + (((unsigned)(a0 + 16)) ^ swzA));

            const int d0 = ch * CH + wv * 64 + c * 32 + lg * 8 - s;  // keep iff (unsigned)(col-s) >= 819
            s16x8 afrag;
            #pragma unroll
            for (int j = 0; j < 4; ++j) {
                float va = ((unsigned)(d0 + j)     >= BLKLEN) ? xa[j] : 0.f;
                float vb = ((unsigned)(d0 + 4 + j) >= BLKLEN) ? xb[j] : 0.f;
                afrag[j]     = (short)f2bf(va);
                afrag[j + 4] = (short)f2bf(vb);
            }

            #pragma unroll
            for (int t = 0; t < 4; ++t)
                acc[t] = __builtin_amdgcn_mfma_f32_16x16x32_bf16(afrag, bf[c][t], acc[t], 0, 0, 0);
        }
    }

    // Cross-wave reduce: partials -> LDS (aliases stage buffers; all staging
    // and reads are done, but other waves may lag -> barrier first).
    __syncthreads();
    float (*plds)[16][64] = reinterpret_cast<float (*)[16][64]>(&lds[0][0][0][0]);  // 32 KB
    #pragma unroll
    for (int t = 0; t < 4; ++t)
        #pragma unroll
        for (int i = 0; i < 4; ++i)
            plds[wv][lg * 4 + i][t * 16 + l16] = acc[t][i];
    __syncthreads();

    const int row = tid >> 5;                // 0..15
    const int col = (tid & 31) * 2;          // 0,2,..,62
    f32x2 sum = (f32x2){bias[col], bias[col + 1]};
    #pragma unroll
    for (int w = 0; w < NWAVES; ++w) {
        sum[0] += plds[w][row][col];
        sum[1] += plds[w][row][col + 1];
    }
    *reinterpret_cast<f32x2*>(out + (size_t)(row_base + row) * NCLS + col) = sum;
}

extern "C" void kernel_launch(void* const* d_in, const int* in_sizes, int n_in,
                              void* d_out, int out_size, void* d_ws, size_t ws_size,
                              hipStream_t stream) {
    const float* x      = (const float*)d_in[0];
    const float* W      = (const float*)d_in[1];
    const float* b      = (const float*)d_in[2];
    const int*   starts = (const int*)d_in[3];
    float*       out    = (float*)d_out;

    const size_t wbytes = (size_t)NCLS * CDIM * sizeof(unsigned short);  // 512 KB
    if (ws_size >= wbytes) {
        unsigned short* Wfm = (unsigned short*)d_ws;
        convert_w_fragmajor<<<128, 256, 0, stream>>>(W, Wfm);
        dropblock_gemm_kernel<true><<<BROWS / 16, 512, 0, stream>>>(x, W, Wfm, b, starts, out);
    } else {
        dropblock_gemm_kernel<false><<<BROWS / 16, 512, 0, stream>>>(x, W, nullptr, b, starts, out);
    }
}

// Round 7
// 60.094 us; speedup vs baseline: 2.9761x; 1.0875x over previous
//
#include <hip/hip_runtime.h>
#include <stdint.h>

#define BROWS 16384
#define CDIM  4096
#define NCLS  64
#define BLKLEN 819u
#define NWAVES 8
#define MROWS 32                  // rows per block
#define CH 256                    // block K-step per chunk (floats); wave slice = 32
#define NCHUNK (CDIM / CH)        // 16

typedef __attribute__((ext_vector_type(4))) float f32x4;
typedef __attribute__((ext_vector_type(8))) short s16x8;   // 8 bf16 - MFMA A/B frag

// fp32 -> bf16 bits, round-to-nearest-even
static __device__ __forceinline__ unsigned short f2bf(float f) {
    union { float f; unsigned u; } v; v.f = f;
    unsigned u = v.u;
    u += 0x7FFFu + ((u >> 16) & 1u);
    return (unsigned short)(u >> 16);
}

static __device__ __forceinline__ void gload_lds16(const void* g, void* l) {
    __builtin_amdgcn_global_load_lds(
        (const __attribute__((address_space(1))) unsigned int*)g,
        (__attribute__((address_space(3))) unsigned int*)l,
        16, 0, 0);
}

// One-time W relayout to FRAGMENT-MAJOR bf16:
// unit u = (kk*4 + t)*64 + lane (16B each) holds bf16x8 of
//   W[t*16 + (lane&15)][kk*32 + (lane>>4)*8 .. +8)
__global__ __launch_bounds__(256) void convert_w_fragmajor(const float* __restrict__ W,
                                                           unsigned short* __restrict__ Wfm) {
    const int u    = blockIdx.x * 256 + threadIdx.x;   // 0..32767
    const int lane = u & 63;
    const int t    = (u >> 6) & 3;
    const int kk   = u >> 8;
    const int row  = t * 16 + (lane & 15);
    const int col  = kk * 32 + (lane >> 4) * 8;
    const float* p = W + (size_t)row * CDIM + col;
    f32x4 a = *reinterpret_cast<const f32x4*>(p);
    f32x4 b = *reinterpret_cast<const f32x4*>(p + 4);
    s16x8 o;
    #pragma unroll
    for (int j = 0; j < 4; ++j) {
        o[j]     = (short)f2bf(a[j]);
        o[j + 4] = (short)f2bf(b[j]);
    }
    *reinterpret_cast<s16x8*>(Wfm + (size_t)u * 8) = o;
}

// Masked skinny GEMM: out[16384,64] = mask(x) @ W^T + b
// Block = 32 rows x 8 waves (512 thr), split-K (wave wv owns cols
// ch*256 + wv*32 .. +32 of each chunk). Wave-private double-buffered LDS
// staging (4KB x 2) + register-prefetched W (1 chunk ahead) + counted vmcnt.
// No __syncthreads in the main loop.
template<bool PRECONV>
__global__ __launch_bounds__(512, 4) void dropblock_gemm_kernel(
    const float* __restrict__ x,
    const float* __restrict__ Wf,            // fp32 W (fallback)
    const unsigned short* __restrict__ Wfm,  // frag-major bf16 W
    const float* __restrict__ bias,
    const int* __restrict__ starts,
    float* __restrict__ out)
{
    __shared__ float lds[NWAVES][2][MROWS][32]; // 64 KB; 8 KB private per wave
    const int tid  = threadIdx.x;
    const int lane = tid & 63;
    const int wv   = tid >> 6;               // wave 0..7 -> K-slice
    const int l16  = lane & 15;
    const int lg   = lane >> 4;              // 0..3
    const int row_base = blockIdx.x * MROWS;

    const int s0 = starts[row_base + l16];
    const int s1 = starts[row_base + 16 + l16];
    const unsigned swzA = (unsigned)((l16 & 7) << 4);
    char* mybuf = (char*)&lds[wv][0][0][0];

    f32x4 acc[2][4];
    #pragma unroll
    for (int f = 0; f < 2; ++f)
        #pragma unroll
        for (int t = 0; t < 4; ++t) acc[f][t] = (f32x4){0.f, 0.f, 0.f, 0.f};

    // Stage chunk ch (this wave's 32x32 f32 subtile) into private buffer b.
    // LDS linear 16B unit u = i*64+lane -> row r = u>>3 = i*8+(lane>>3),
    // within-row slot lane&7; source pre-swizzled by ((r&7)<<4).
    auto stage = [&](int ch, int b) {
        char* lb = mybuf + b * 4096;
        const size_t colbase = (size_t)ch * CH + (size_t)wv * 32;
        #pragma unroll
        for (int i = 0; i < 4; ++i) {
            const int r = i * 8 + (lane >> 3);
            const unsigned wb = ((unsigned)((lane & 7) * 16)) ^ ((unsigned)((r & 7) << 4));
            const char* g = (const char*)x + ((size_t)(row_base + r) * CDIM + colbase) * 4 + wb;
            gload_lds16(g, lb + i * 1024);
        }
    };

    s16x8 wfr[2][4];                          // W frag double-buffer (static idx after unroll)
    auto loadW = [&](int ch, int b) {
        const int kk = ch * 8 + wv;           // global k0/32 index for this wave
        #pragma unroll
        for (int t = 0; t < 4; ++t)
            wfr[b][t] = *reinterpret_cast<const s16x8*>(
                Wfm + ((size_t)((kk * 4 + t) * 64 + lane)) * 8);
    };

    stage(0, 0);
    if (PRECONV) loadW(0, 0);

    #pragma unroll
    for (int ch = 0; ch < NCHUNK; ++ch) {
        const int b = ch & 1;

        if (ch + 1 < NCHUNK) {
            if (PRECONV) loadW(ch + 1, b ^ 1);
            stage(ch + 1, b ^ 1);
        }

        __builtin_amdgcn_sched_barrier(0);
        if (ch + 1 < NCHUNK) {
            if (PRECONV) asm volatile("s_waitcnt vmcnt(8)" ::: "memory");  // drain stage(ch)+W(ch)
            else         asm volatile("s_waitcnt vmcnt(4)" ::: "memory");  // drain stage(ch)
        } else {
            asm volatile("s_waitcnt vmcnt(0)" ::: "memory");
        }
        __builtin_amdgcn_sched_barrier(0);

        const char* lb = mybuf + b * 4096;
        #pragma unroll
        for (int f = 0; f < 2; ++f) {
            const int row = f * 16 + l16;
            const unsigned a0 = (unsigned)(row * 128 + lg * 32);
            f32x4 xa = *reinterpret_cast<const f32x4*>(lb + (a0 ^ swzA));
            f32x4 xb = *reinterpret_cast<const f32x4*>(lb + ((a0 + 16) ^ swzA));

            const int d0 = ch * CH + wv * 32 + lg * 8 - (f ? s1 : s0);
            s16x8 afrag;
            #pragma unroll
            for (int j = 0; j < 4; ++j) {
                float va = ((unsigned)(d0 + j)     >= BLKLEN) ? xa[j] : 0.f;
                float vb = ((unsigned)(d0 + 4 + j) >= BLKLEN) ? xb[j] : 0.f;
                afrag[j]     = (short)f2bf(va);
                afrag[j + 4] = (short)f2bf(vb);
            }

            #pragma unroll
            for (int t = 0; t < 4; ++t) {
                s16x8 bfrag;
                if (PRECONV) {
                    bfrag = wfr[b][t];
                } else {
                    const int kk = ch * 8 + wv;
                    const float* wrow = Wf + (size_t)(t * 16 + l16) * CDIM + kk * 32 + lg * 8;
                    f32x4 wa = *reinterpret_cast<const f32x4*>(wrow);
                    f32x4 wb2 = *reinterpret_cast<const f32x4*>(wrow + 4);
                    #pragma unroll
                    for (int j = 0; j < 4; ++j) {
                        bfrag[j]     = (short)f2bf(wa[j]);
                        bfrag[j + 4] = (short)f2bf(wb2[j]);
                    }
                }
                acc[f][t] = __builtin_amdgcn_mfma_f32_16x16x32_bf16(afrag, bfrag, acc[f][t], 0, 0, 0);
            }
        }
    }

    // Partials: each wave writes its OWN 8KB region (plds[wv] == mybuf), so no
    // barrier needed before the write; one barrier before the cross-wave read.
    float (*plds)[MROWS][64] = reinterpret_cast<float (*)[MROWS][64]>(&lds[0][0][0][0]); // 64 KB
    #pragma unroll
    for (int f = 0; f < 2; ++f)
        #pragma unroll
        for (int t = 0; t < 4; ++t)
            #pragma unroll
            for (int i = 0; i < 4; ++i)
                plds[wv][f * 16 + lg * 4 + i][t * 16 + l16] = acc[f][t][i];
    __syncthreads();

    // Reduce 8 partials + bias. 512 threads x f32x4 = 2048 outputs.
    const int row  = tid >> 4;               // 0..31
    const int col4 = (tid & 15) * 4;         // 0,4,..,60
    f32x4 sum = *reinterpret_cast<const f32x4*>(bias + col4);
    #pragma unroll
    for (int w = 0; w < NWAVES; ++w)
        sum += *reinterpret_cast<const f32x4*>(&plds[w][row][col4]);
    *reinterpret_cast<f32x4*>(out + (size_t)(row_base + row) * NCLS + col4) = sum;
}

extern "C" void kernel_launch(void* const* d_in, const int* in_sizes, int n_in,
                              void* d_out, int out_size, void* d_ws, size_t ws_size,
                              hipStream_t stream) {
    const float* x      = (const float*)d_in[0];
    const float* W      = (const float*)d_in[1];
    const float* b      = (const float*)d_in[2];
    const int*   starts = (const int*)d_in[3];
    float*       out    = (float*)d_out;

    const size_t wbytes = (size_t)NCLS * CDIM * sizeof(unsigned short);  // 512 KB
    if (ws_size >= wbytes) {
        unsigned short* Wfm = (unsigned short*)d_ws;
        convert_w_fragmajor<<<128, 256, 0, stream>>>(W, Wfm);
        dropblock_gemm_kernel<true><<<BROWS / MROWS, 512, 0, stream>>>(x, W, Wfm, b, starts, out);
    } else {
        dropblock_gemm_kernel<false><<<BROWS / MROWS, 512, 0, stream>>>(x, W, nullptr, b, starts, out);
    }
}

// Round 8
// 49.390 us; speedup vs baseline: 3.6212x; 1.2167x over previous
//
#include <hip/hip_runtime.h>
#include <stdint.h>

#define BROWS 16384
#define CDIM  4096
#define NCLS  64
#define BLKLEN 819u
#define NWAVES 8
#define MROWS 32                  // rows per block
#define CH 256                    // block K-step per chunk (floats); wave slice = 32
#define NCHUNK (CDIM / CH)        // 16

typedef __attribute__((ext_vector_type(4))) float f32x4;
typedef __attribute__((ext_vector_type(8))) short s16x8;   // 8 bf16 - MFMA A/B frag

// fp32 -> bf16 bits, round-to-nearest-even
static __device__ __forceinline__ unsigned short f2bf(float f) {
    union { float f; unsigned u; } v; v.f = f;
    unsigned u = v.u;
    u += 0x7FFFu + ((u >> 16) & 1u);
    return (unsigned short)(u >> 16);
}

static __device__ __forceinline__ void gload_lds16(const void* g, void* l) {
    __builtin_amdgcn_global_load_lds(
        (const __attribute__((address_space(1))) unsigned int*)g,
        (__attribute__((address_space(3))) unsigned int*)l,
        16, 0, 0);
}

// One-time W relayout to FRAGMENT-MAJOR bf16:
// unit u = (kk*4 + t)*64 + lane (16B each) holds bf16x8 of
//   W[t*16 + (lane&15)][kk*32 + (lane>>4)*8 .. +8)
__global__ __launch_bounds__(256) void convert_w_fragmajor(const float* __restrict__ W,
                                                           unsigned short* __restrict__ Wfm) {
    const int u    = blockIdx.x * 256 + threadIdx.x;   // 0..32767
    const int lane = u & 63;
    const int t    = (u >> 6) & 3;
    const int kk   = u >> 8;
    const int row  = t * 16 + (lane & 15);
    const int col  = kk * 32 + (lane >> 4) * 8;
    const float* p = W + (size_t)row * CDIM + col;
    f32x4 a = *reinterpret_cast<const f32x4*>(p);
    f32x4 b = *reinterpret_cast<const f32x4*>(p + 4);
    s16x8 o;
    #pragma unroll
    for (int j = 0; j < 4; ++j) {
        o[j]     = (short)f2bf(a[j]);
        o[j + 4] = (short)f2bf(b[j]);
    }
    *reinterpret_cast<s16x8*>(Wfm + (size_t)u * 8) = o;
}

// Masked skinny GEMM: out[16384,64] = mask(x) @ W^T + b
// Block = 32 rows x 8 waves (512 thr), split-K. Wave-private double-buffered
// LDS staging + reg-prefetched W + counted vmcnt, no main-loop barriers.
// NEW: stage lanes whose 16B unit is fully inside the masked window are
// address-CLAMPED to one shared line (instruction count stays static for the
// vmcnt discipline; ~19% less x HBM traffic; afrag cndmask zeroes by index).
template<bool PRECONV>
__global__ __launch_bounds__(512, 4) void dropblock_gemm_kernel(
    const float* __restrict__ x,
    const float* __restrict__ Wf,            // fp32 W (fallback)
    const unsigned short* __restrict__ Wfm,  // frag-major bf16 W
    const float* __restrict__ bias,
    const int* __restrict__ starts,
    float* __restrict__ out)
{
    __shared__ float lds[NWAVES][2][MROWS][32]; // 64 KB; 8 KB private per wave
    const int tid  = threadIdx.x;
    const int lane = tid & 63;
    const int wv   = tid >> 6;               // wave 0..7 -> K-slice
    const int l16  = lane & 15;
    const int lg   = lane >> 4;              // 0..3
    const int row_base = blockIdx.x * MROWS;

    const int s0 = starts[row_base + l16];
    const int s1 = starts[row_base + 16 + l16];
    // starts for this lane's STAGE rows r = i*8 + (lane>>3)
    int sr[4];
    #pragma unroll
    for (int i = 0; i < 4; ++i) sr[i] = starts[row_base + i * 8 + (lane >> 3)];

    const unsigned swzA = (unsigned)((l16 & 7) << 4);
    char* mybuf = (char*)&lds[wv][0][0][0];

    f32x4 acc[2][4];
    #pragma unroll
    for (int f = 0; f < 2; ++f)
        #pragma unroll
        for (int t = 0; t < 4; ++t) acc[f][t] = (f32x4){0.f, 0.f, 0.f, 0.f};

    // Stage chunk ch (this wave's 32x32 f32 subtile) into private buffer b.
    // LDS linear 16B unit u = i*64+lane -> row r = i*8+(lane>>3), slot lane&7;
    // source pre-swizzled by ((r&7)<<4) so reads XOR the same involution.
    auto stage = [&](int ch, int b) {
        char* lb = mybuf + b * 4096;
        const size_t colbase = (size_t)ch * CH + (size_t)wv * 32;
        const char* gclamp = (const char*)x + ((size_t)row_base * CDIM + colbase) * 4;
        #pragma unroll
        for (int i = 0; i < 4; ++i) {
            const int r = i * 8 + (lane >> 3);
            const unsigned wb = ((unsigned)((lane & 7) * 16)) ^ ((unsigned)((r & 7) << 4));
            // first col of this lane's 4-float unit:
            const int c0 = (int)colbase + (int)(wb >> 2);
            // fully masked iff [c0, c0+4) subset of [sr, sr+819)
            const bool fullmask = (unsigned)(c0 - sr[i]) <= (BLKLEN - 4u);
            const char* gnorm = (const char*)x
                + ((size_t)(row_base + r) * CDIM + colbase) * 4 + wb;
            const char* g = fullmask ? gclamp : gnorm;
            gload_lds16(g, lb + i * 1024);
        }
    };

    s16x8 wfr[2][4];                          // W frag double-buffer
    auto loadW = [&](int ch, int b) {
        const int kk = ch * 8 + wv;           // global k0/32 index for this wave
        #pragma unroll
        for (int t = 0; t < 4; ++t)
            wfr[b][t] = *reinterpret_cast<const s16x8*>(
                Wfm + ((size_t)((kk * 4 + t) * 64 + lane)) * 8);
    };

    stage(0, 0);
    if (PRECONV) loadW(0, 0);

    #pragma unroll
    for (int ch = 0; ch < NCHUNK; ++ch) {
        const int b = ch & 1;

        if (ch + 1 < NCHUNK) {
            if (PRECONV) loadW(ch + 1, b ^ 1);
            stage(ch + 1, b ^ 1);
        }

        __builtin_amdgcn_sched_barrier(0);
        if (ch + 1 < NCHUNK) {
            if (PRECONV) asm volatile("s_waitcnt vmcnt(8)" ::: "memory");  // drain stage(ch)+W(ch)
            else         asm volatile("s_waitcnt vmcnt(4)" ::: "memory");  // drain stage(ch)
        } else {
            asm volatile("s_waitcnt vmcnt(0)" ::: "memory");
        }
        __builtin_amdgcn_sched_barrier(0);

        const char* lb = mybuf + b * 4096;
        #pragma unroll
        for (int f = 0; f < 2; ++f) {
            const int row = f * 16 + l16;
            const unsigned a0 = (unsigned)(row * 128 + lg * 32);
            f32x4 xa = *reinterpret_cast<const f32x4*>(lb + (a0 ^ swzA));
            f32x4 xb = *reinterpret_cast<const f32x4*>(lb + ((a0 + 16) ^ swzA));

            const int d0 = ch * CH + wv * 32 + lg * 8 - (f ? s1 : s0);
            s16x8 afrag;
            #pragma unroll
            for (int j = 0; j < 4; ++j) {
                float va = ((unsigned)(d0 + j)     >= BLKLEN) ? xa[j] : 0.f;
                float vb = ((unsigned)(d0 + 4 + j) >= BLKLEN) ? xb[j] : 0.f;
                afrag[j]     = (short)f2bf(va);
                afrag[j + 4] = (short)f2bf(vb);
            }

            #pragma unroll
            for (int t = 0; t < 4; ++t) {
                s16x8 bfrag;
                if (PRECONV) {
                    bfrag = wfr[b][t];
                } else {
                    const int kk = ch * 8 + wv;
                    const float* wrow = Wf + (size_t)(t * 16 + l16) * CDIM + kk * 32 + lg * 8;
                    f32x4 wa = *reinterpret_cast<const f32x4*>(wrow);
                    f32x4 wb2 = *reinterpret_cast<const f32x4*>(wrow + 4);
                    #pragma unroll
                    for (int j = 0; j < 4; ++j) {
                        bfrag[j]     = (short)f2bf(wa[j]);
                        bfrag[j + 4] = (short)f2bf(wb2[j]);
                    }
                }
                acc[f][t] = __builtin_amdgcn_mfma_f32_16x16x32_bf16(afrag, bfrag, acc[f][t], 0, 0, 0);
            }
        }
    }

    // Partials: each wave writes its OWN 8KB region; barrier only before the
    // cross-wave read.
    float (*plds)[MROWS][64] = reinterpret_cast<float (*)[MROWS][64]>(&lds[0][0][0][0]); // 64 KB
    #pragma unroll
    for (int f = 0; f < 2; ++f)
        #pragma unroll
        for (int t = 0; t < 4; ++t)
            #pragma unroll
            for (int i = 0; i < 4; ++i)
                plds[wv][f * 16 + lg * 4 + i][t * 16 + l16] = acc[f][t][i];
    __syncthreads();

    // Reduce 8 partials + bias. 512 threads x f32x4 = 2048 outputs.
    const int row  = tid >> 4;               // 0..31
    const int col4 = (tid & 15) * 4;         // 0,4,..,60
    f32x4 sum = *reinterpret_cast<const f32x4*>(bias + col4);
    #pragma unroll
    for (int w = 0; w < NWAVES; ++w)
        sum += *reinterpret_cast<const f32x4*>(&plds[w][row][col4]);
    *reinterpret_cast<f32x4*>(out + (size_t)(row_base + row) * NCLS + col4) = sum;
}

extern "C" void kernel_launch(void* const* d_in, const int* in_sizes, int n_in,
                              void* d_out, int out_size, void* d_ws, size_t ws_size,
                              hipStream_t stream) {
    const float* x      = (const float*)d_in[0];
    const float* W      = (const float*)d_in[1];
    const float* b      = (const float*)d_in[2];
    const int*   starts = (const int*)d_in[3];
    float*       out    = (float*)d_out;

    const size_t wbytes = (size_t)NCLS * CDIM * sizeof(unsigned short);  // 512 KB
    if (ws_size >= wbytes) {
        unsigned short* Wfm = (unsigned short*)d_ws;
        convert_w_fragmajor<<<128, 256, 0, stream>>>(W, Wfm);
        dropblock_gemm_kernel<true><<<BROWS / MROWS, 512, 0, stream>>>(x, W, Wfm, b, starts, out);
    } else {
        dropblock_gemm_kernel<false><<<BROWS / MROWS, 512, 0, stream>>>(x, W, nullptr, b, starts, out);
    }
}